// Round 12
// baseline (232.129 us; speedup 1.0000x reference)
//
#include <hip/hip_runtime.h>
#include <stdint.h>

#define NN 100000   // nodes
#define NREL 3
#define NE 200000   // edges per relation
#define F 128       // feature dim (in = hid = out)
#define NQ 4096

#define NBUCK (NREL * NN)          // 300000 buckets
#define SCAN_PER_BLK 1024          // elements per scan block (256 thr x 4)
#define NSCANBLK ((NBUCK + SCAN_PER_BLK - 1) / SCAN_PER_BLK)  // 293

// prep_kernel index-space partition
#define WCVT_N (2 * NREL * F * F)              // 98304
#define BIAS_N 256
#define CVTX_N (NN * F / 8)                    // 1600000
#define CNTZ_N (2 * NREL * NN)                 // 600000
#define PREP_N (WCVT_N + BIAS_N + CVTX_N + CNTZ_N)

typedef float fx4 __attribute__((ext_vector_type(4)));
typedef unsigned short u16x8 __attribute__((ext_vector_type(8)));
typedef __bf16 bf16x8 __attribute__((ext_vector_type(8)));

__device__ __forceinline__ unsigned short f2bf(float f) {
  uint32_t u = __builtin_bit_cast(uint32_t, f);
  uint32_t r = u + 0x7FFFu + ((u >> 16) & 1u);
  return (unsigned short)(r >> 16);
}
__device__ __forceinline__ float bf2f(unsigned short u) {
  return __builtin_bit_cast(float, (uint32_t)u << 16);
}

// ---- fused prep: Wt conversion + bias sums + X->bf16 + cnt zeroing (1 launch) ----
__global__ void prep_kernel(const float* __restrict__ W1, const float* __restrict__ W2,
                            const float* __restrict__ b1, const float* __restrict__ b2,
                            const float* __restrict__ emb,
                            unsigned short* __restrict__ Wtb, float* __restrict__ bsum,
                            unsigned short* __restrict__ xb, int* __restrict__ cnt) {
  int i = blockIdx.x * blockDim.x + threadIdx.x;
  if (i < WCVT_N) {
    // Wtb[layer][rel][n][k] = bf16(W[layer][rel][k][n])
    int l = i / (NREL * F * F);
    int rem = i % (NREL * F * F);
    int r = rem / (F * F);
    int nk = rem % (F * F);
    int n = nk >> 7, k = nk & 127;
    const float* W = l ? W2 : W1;
    Wtb[i] = f2bf(W[r * F * F + k * F + n]);
  } else if (i < WCVT_N + BIAS_N) {
    int t = i - WCVT_N;
    int l = t >> 7, f = t & 127;
    const float* b = l ? b2 : b1;
    bsum[l * F + f] = b[f] + b[F + f] + b[2 * F + f];
  } else if (i < WCVT_N + BIAS_N + CVTX_N) {
    int j = i - (WCVT_N + BIAS_N);
    const float* p = emb + (size_t)j * 8;
    unsigned short tmp[8];
#pragma unroll
    for (int e = 0; e < 8; ++e) tmp[e] = f2bf(p[e]);
    *reinterpret_cast<u16x8*>(xb + (size_t)j * 8) = *reinterpret_cast<u16x8*>(tmp);
  } else if (i < PREP_N) {
    cnt[i - (WCVT_N + BIAS_N + CVTX_N)] = 0;
  }
}

// ---- integer degree counts: cnt[0..3NN) = out-deg per rel, cnt[3NN..6NN) = in-deg ----
__global__ void cnt_kernel(const int* __restrict__ es, const int* __restrict__ ed,
                           int* __restrict__ cnt) {
  int i = blockIdx.x * blockDim.x + threadIdx.x;
  if (i >= NREL * NE) return;
  int r = i / NE;
  atomicAdd(&cnt[r * NN + es[i]], 1);
  atomicAdd(&cnt[NREL * NN + r * NN + ed[i]], 1);
}

// ---- deterministic hierarchical exclusive scan over cnt_in (no global atomics) ----
// A: per-block (1024 elems) totals
__global__ __launch_bounds__(256) void scanA_kernel(const int* __restrict__ cnt_in,
                                                    int* __restrict__ bsumA) {
  int b = blockIdx.x, t = threadIdx.x;
  int base = b * SCAN_PER_BLK + t * 4;
  int s = 0;
#pragma unroll
  for (int k = 0; k < 4; ++k) {
    int i = base + k;
    if (i < NBUCK) s += cnt_in[i];
  }
#pragma unroll
  for (int d = 1; d < 64; d <<= 1) s += __shfl_xor(s, d);
  __shared__ int ws[4];
  if ((t & 63) == 0) ws[t >> 6] = s;
  __syncthreads();
  if (t == 0) bsumA[b] = ws[0] + ws[1] + ws[2] + ws[3];
}

// BC merged: each block computes its own base = sum(bsumA[0..b)) then rescans its chunk
__global__ __launch_bounds__(256) void scanBC_kernel(const int* __restrict__ cnt_in,
                                                     const int* __restrict__ bsumA,
                                                     int2* __restrict__ scb,
                                                     int* __restrict__ fill) {
  int b = blockIdx.x, t = threadIdx.x;
  // block base: sum of preceding block totals (<=293 ints)
  int pre = 0;
  for (int i = t; i < b; i += 256) pre += bsumA[i];
#pragma unroll
  for (int d = 1; d < 64; d <<= 1) pre += __shfl_xor(pre, d);
  __shared__ int wsum[4];
  if ((t & 63) == 0) wsum[t >> 6] = pre;
  __syncthreads();
  const int base0 = wsum[0] + wsum[1] + wsum[2] + wsum[3];

  int base = b * SCAN_PER_BLK + t * 4;
  int c[4];
  int s = 0;
#pragma unroll
  for (int k = 0; k < 4; ++k) {
    int i = base + k;
    c[k] = (i < NBUCK) ? cnt_in[i] : 0;
    s += c[k];
  }
  int lane = t & 63, w = t >> 6;
  int sc = s;
#pragma unroll
  for (int d = 1; d < 64; d <<= 1) {
    int o = __shfl_up(sc, d);
    if (lane >= d) sc += o;
  }
  int thr_excl = sc - s;
  __shared__ int wtot[4];
  if (lane == 63) wtot[w] = sc;
  __syncthreads();
  int wave_off = 0;
#pragma unroll
  for (int ww = 0; ww < 3; ++ww) wave_off += (ww < w) ? wtot[ww] : 0;
  int start = base0 + wave_off + thr_excl;
#pragma unroll
  for (int k = 0; k < 4; ++k) {
    int i = base + k;
    if (i < NBUCK) {
      scb[i] = make_int2(start, c[k]);
      fill[i] = 0;
      start += c[k];
    }
  }
}

// place each edge into its dst bucket; payload = {src, w = rsqrt(outdeg)*rsqrt(indeg)}
__global__ void fill_kernel(const int* __restrict__ es, const int* __restrict__ ed,
                            const int* __restrict__ cnt,
                            const int2* __restrict__ scb, int* __restrict__ fill,
                            int2* __restrict__ epay) {
  int i = blockIdx.x * blockDim.x + threadIdx.x;
  if (i >= NREL * NE) return;
  int r = i / NE;
  int s = es[i], d = ed[i];
  int b = r * NN + d;
  int2 m = scb[b];
  int pos = m.x + atomicAdd(&fill[b], 1);
  int co = cnt[r * NN + s];
  float w = rsqrtf((float)co) * rsqrtf((float)m.y);
  epay[pos] = make_int2(s, __builtin_bit_cast(int, w));
}

// ---- aggregate-first: Z[r][m][f] = sum_{e in bucket(r,n)} w_e * X[src_e][f]
// 16 lanes per m-row, 4 rows per wave; Z row stride per relation = Ms (128-padded).
__global__ __launch_bounds__(256) void aggz_kernel(const unsigned short* __restrict__ X,
                                                   const int2* __restrict__ scb,
                                                   const int2* __restrict__ epay,
                                                   unsigned short* __restrict__ Z,
                                                   int M, int Ms) {
  const int r = blockIdx.y;
  const int t = threadIdx.x;
  const int lane = t & 63;
  const int m = blockIdx.x * 16 + (t >> 6) * 4 + (lane >> 4);
  const int j = lane & 15;
  if (m >= M) return;
  int2 meta = scb[r * NN + m];
  const int2* ep = epay + meta.x;
  const int c = meta.y;

  float ps[8];
#pragma unroll
  for (int k = 0; k < 8; ++k) ps[k] = 0.f;

  int i = 0;
  for (; i + 2 <= c; i += 2) {
    int2 p0 = ep[i], p1 = ep[i + 1];
    float w0 = __builtin_bit_cast(float, p0.y);
    float w1 = __builtin_bit_cast(float, p1.y);
    u16x8 v0 = *reinterpret_cast<const u16x8*>(X + ((size_t)p0.x << 7) + j * 8);
    u16x8 v1 = *reinterpret_cast<const u16x8*>(X + ((size_t)p1.x << 7) + j * 8);
#pragma unroll
    for (int k = 0; k < 8; ++k)
      ps[k] = fmaf(bf2f(v1[k]), w1, fmaf(bf2f(v0[k]), w0, ps[k]));
  }
  if (i < c) {
    int2 p0 = ep[i];
    float w0 = __builtin_bit_cast(float, p0.y);
    u16x8 v0 = *reinterpret_cast<const u16x8*>(X + ((size_t)p0.x << 7) + j * 8);
#pragma unroll
    for (int k = 0; k < 8; ++k) ps[k] = fmaf(bf2f(v0[k]), w0, ps[k]);
  }

  unsigned short tmp[8];
#pragma unroll
  for (int k = 0; k < 8; ++k) tmp[k] = f2bf(ps[k]);
  *reinterpret_cast<u16x8*>(Z + (((size_t)r * Ms + m) << 7) + j * 8) =
      *reinterpret_cast<u16x8*>(tmp);
}

// ---- layer-1 GEMM: global_load_lds staging + 2-phase pipeline (R11-proven, 50us) ----
#define GBM 128
__global__ __launch_bounds__(512) void gemmp_kernel(const unsigned short* __restrict__ Z,
                                                    const unsigned short* __restrict__ Wt3,
                                                    const float* __restrict__ bsum,
                                                    unsigned short* __restrict__ outp,
                                                    int M, int Ms) {
  __shared__ unsigned short Abuf[2][GBM * F];   // 2 x 32 KB
  const int t = threadIdx.x;
  const int m0 = blockIdx.x * GBM;
  const int lane = t & 63, w = t >> 6;
  const int wm = w >> 2, wn = w & 3;            // 2m x 4n wave grid
  const int r0 = lane & 15, kq = lane >> 4;

  fx4 acc[4][2];
#pragma unroll
  for (int mt = 0; mt < 4; ++mt)
#pragma unroll
    for (int nt = 0; nt < 2; ++nt) acc[mt][nt] = (fx4){0.f, 0.f, 0.f, 0.f};

  {
    const unsigned short* Zr = Z + (size_t)m0 * F;
#pragma unroll
    for (int i = 0; i < 4; ++i) {
      int slot = i * 512 + t;
      int row = slot >> 4, s = slot & 15;
      __builtin_amdgcn_global_load_lds(
          (const __attribute__((address_space(1))) uint32_t*)(
              Zr + ((size_t)row << 7) + ((s ^ (row & 7)) << 3)),
          (__attribute__((address_space(3))) uint32_t*)&Abuf[0][slot * 8], 16, 0, 0);
    }
  }
  __syncthreads();

  int cur = 0;
  for (int r = 0; r < NREL; ++r) {
    bf16x8 bfrag[2][4];
    const unsigned short* Wt = Wt3 + (size_t)r * F * F;
#pragma unroll
    for (int nt = 0; nt < 2; ++nt)
#pragma unroll
      for (int kb = 0; kb < 4; ++kb)
        bfrag[nt][kb] = __builtin_bit_cast(bf16x8,
            *reinterpret_cast<const u16x8*>(
                Wt + (wn * 32 + nt * 16 + r0) * F + (4 * kb + kq) * 8));

    if (r + 1 < NREL) {
      const unsigned short* Zr = Z + ((size_t)(r + 1) * Ms + m0) * F;
#pragma unroll
      for (int i = 0; i < 4; ++i) {
        int slot = i * 512 + t;
        int row = slot >> 4, s = slot & 15;
        __builtin_amdgcn_global_load_lds(
            (const __attribute__((address_space(1))) uint32_t*)(
                Zr + ((size_t)row << 7) + ((s ^ (row & 7)) << 3)),
            (__attribute__((address_space(3))) uint32_t*)&Abuf[cur ^ 1][slot * 8],
            16, 0, 0);
      }
    }

#pragma unroll
    for (int kb = 0; kb < 4; ++kb) {
      const int cs = ((kb * 4 + kq) ^ (r0 & 7)) * 8;
      bf16x8 a[4];
#pragma unroll
      for (int mt = 0; mt < 4; ++mt)
        a[mt] = __builtin_bit_cast(bf16x8,
            *reinterpret_cast<const u16x8*>(&Abuf[cur][(wm * 64 + mt * 16 + r0) * F + cs]));
#pragma unroll
      for (int mt = 0; mt < 4; ++mt)
#pragma unroll
        for (int nt = 0; nt < 2; ++nt)
          acc[mt][nt] = __builtin_amdgcn_mfma_f32_16x16x32_bf16(a[mt], bfrag[nt][kb],
                                                                acc[mt][nt], 0, 0, 0);
    }

    __syncthreads();
    cur ^= 1;
  }

#pragma unroll
  for (int mt = 0; mt < 4; ++mt) {
    const int rbase = m0 + wm * 64 + mt * 16 + kq * 4;
#pragma unroll
    for (int nt = 0; nt < 2; ++nt) {
      int col = wn * 32 + nt * 16 + r0;
      float bb = bsum[col];
#pragma unroll
      for (int reg = 0; reg < 4; ++reg) {
        int gm = rbase + reg;
        if (gm < M) outp[(size_t)gm * F + col] = f2bf(tanhf(acc[mt][nt][reg] + bb));
      }
    }
  }
}

// ---- layer-2 fused agg+GEMM (R9-proven structure; used ONLY at M=8192) ----
#define LDP 136
__global__ __launch_bounds__(512) void fused2_kernel(const unsigned short* __restrict__ X,
                                                     const int2* __restrict__ scb,
                                                     const int2* __restrict__ epay,
                                                     const int* __restrict__ qsrc,
                                                     const int* __restrict__ qdst,
                                                     const unsigned short* __restrict__ Wt3,
                                                     const float* __restrict__ bsum,
                                                     float* __restrict__ outp, int M) {
  __shared__ unsigned short Ztd[2][GBM * LDP];  // double-buffered, ~69.6 KB
  const int t = threadIdx.x;
  const int m0 = blockIdx.x * GBM;
  const int lane = t & 63, w = t >> 6;
  const int wm = w >> 2, wn = w & 3;
  const int r0 = lane & 15, kq = lane >> 4;
  const int qw = t >> 4, j = t & 15;

  fx4 acc[4][2];
#pragma unroll
  for (int mt = 0; mt < 4; ++mt)
#pragma unroll
    for (int nt = 0; nt < 2; ++nt) acc[mt][nt] = (fx4){0.f, 0.f, 0.f, 0.f};

  for (int r = 0; r < NREL; ++r) {
    unsigned short* Zc = &Ztd[r & 1][0];

    bf16x8 bfrag[2][4];
    const unsigned short* Wt = Wt3 + (size_t)r * F * F;
#pragma unroll
    for (int nt = 0; nt < 2; ++nt)
#pragma unroll
      for (int kb = 0; kb < 4; ++kb)
        bfrag[nt][kb] = __builtin_bit_cast(bf16x8,
            *reinterpret_cast<const u16x8*>(
                Wt + (wn * 32 + nt * 16 + r0) * F + (4 * kb + kq) * 8));

    for (int it = 0; it < 4; ++it) {
      int rr = it * 32 + qw;
      int m = m0 + rr;
      float ps[8];
#pragma unroll
      for (int k = 0; k < 8; ++k) ps[k] = 0.f;
      if (m < M) {
        int n = (m < NQ) ? qsrc[m] : qdst[m - NQ];
        int2 meta = scb[r * NN + n];
        const int2* ep = epay + meta.x;
        const int c = meta.y;
        int i = 0;
        for (; i + 2 <= c; i += 2) {
          int2 p0 = ep[i], p1 = ep[i + 1];
          float w0 = __builtin_bit_cast(float, p0.y);
          float w1 = __builtin_bit_cast(float, p1.y);
          u16x8 v0 = *reinterpret_cast<const u16x8*>(X + ((size_t)p0.x << 7) + j * 8);
          u16x8 v1 = *reinterpret_cast<const u16x8*>(X + ((size_t)p1.x << 7) + j * 8);
#pragma unroll
          for (int k = 0; k < 8; ++k)
            ps[k] = fmaf(bf2f(v1[k]), w1, fmaf(bf2f(v0[k]), w0, ps[k]));
        }
        if (i < c) {
          int2 p0 = ep[i];
          float w0 = __builtin_bit_cast(float, p0.y);
          u16x8 v0 = *reinterpret_cast<const u16x8*>(X + ((size_t)p0.x << 7) + j * 8);
#pragma unroll
          for (int k = 0; k < 8; ++k) ps[k] = fmaf(bf2f(v0[k]), w0, ps[k]);
        }
      }
      unsigned short tmp[8];
#pragma unroll
      for (int k = 0; k < 8; ++k) tmp[k] = f2bf(ps[k]);
      *reinterpret_cast<u16x8*>(&Zc[rr * LDP + j * 8]) = *reinterpret_cast<u16x8*>(tmp);
    }

    __syncthreads();

#pragma unroll
    for (int kb = 0; kb < 4; ++kb) {
      const int cs = (4 * kb + kq) * 8;
      bf16x8 a[4];
#pragma unroll
      for (int mt = 0; mt < 4; ++mt)
        a[mt] = __builtin_bit_cast(bf16x8,
            *reinterpret_cast<const u16x8*>(&Zc[(wm * 64 + mt * 16 + r0) * LDP + cs]));
#pragma unroll
      for (int mt = 0; mt < 4; ++mt)
#pragma unroll
        for (int nt = 0; nt < 2; ++nt)
          acc[mt][nt] = __builtin_amdgcn_mfma_f32_16x16x32_bf16(a[mt], bfrag[nt][kb],
                                                                acc[mt][nt], 0, 0, 0);
    }

    __syncthreads();
  }

#pragma unroll
  for (int mt = 0; mt < 4; ++mt) {
    const int rbase = m0 + wm * 64 + mt * 16 + kq * 4;
#pragma unroll
    for (int nt = 0; nt < 2; ++nt) {
      int col = wn * 32 + nt * 16 + r0;
      float bb = bsum[col];
#pragma unroll
      for (int reg = 0; reg < 4; ++reg) {
        int gm = rbase + reg;
        if (gm < M) outp[(size_t)gm * F + col] = tanhf(acc[mt][nt][reg] + bb);
      }
    }
  }
}

extern "C" void kernel_launch(void* const* d_in, const int* in_sizes, int n_in,
                              void* d_out, int out_size, void* d_ws, size_t ws_size,
                              hipStream_t stream) {
  const float* emb = (const float*)d_in[0];
  const float* W1  = (const float*)d_in[1];
  const float* b1  = (const float*)d_in[2];
  const float* W2  = (const float*)d_in[3];
  const float* b2  = (const float*)d_in[4];
  const int* e_src = (const int*)d_in[5];
  const int* e_dst = (const int*)d_in[6];
  const int* qsrc  = (const int*)d_in[7];
  const int* qdst  = (const int*)d_in[8];
  float* out = (float*)d_out;

  const int MS1 = ((NN + GBM - 1) / GBM) * GBM;   // 100096 (padded Z stride, layer 1)
  const int MQ  = 2 * NQ;                          // 8192

  char* p = (char*)d_ws;
  size_t off = 0;
  auto take = [&](size_t n) { void* q = p + off; off = (off + n + 255) & ~(size_t)255; return q; };
  int* cnt    = (int*)take(2ull * NREL * NN * 4);       // [out|in] counts
  int* blksum = (int*)take((size_t)NSCANBLK * 4);       // scanA block totals
  int2* scb   = (int2*)take((size_t)NBUCK * 8);         // {start, cnt} per bucket
  int* fill   = (int*)take((size_t)NBUCK * 4);
  int2* epay  = (int2*)take((size_t)NREL * NE * 8);     // {src, w}
  unsigned short* Wtb = (unsigned short*)take(2ull * NREL * F * F * 2);
  float* bsum = (float*)take(2ull * F * 4);
  unsigned short* Xb  = (unsigned short*)take((size_t)NN * F * 2);   // h0 / h1 (bf16)
  unsigned short* Z   = (unsigned short*)take((size_t)NREL * MS1 * F * 2);

  int* cnt_in = cnt + (size_t)NREL * NN;

  // 1: prep (Wt cvt + bias sums + X cvt + cnt zero)
  prep_kernel<<<(PREP_N + 255) / 256, 256, 0, stream>>>(W1, W2, b1, b2, emb,
                                                        Wtb, bsum, Xb, cnt);
  // 2: degree counts
  cnt_kernel<<<(NREL * NE + 255) / 256, 256, 0, stream>>>(e_src, e_dst, cnt);
  // 3-4: scan -> {start,cnt} buckets
  scanA_kernel<<<NSCANBLK, 256, 0, stream>>>(cnt_in, blksum);
  scanBC_kernel<<<NSCANBLK, 256, 0, stream>>>(cnt_in, blksum, scb, fill);
  // 5: edge placement
  fill_kernel<<<(NREL * NE + 255) / 256, 256, 0, stream>>>(e_src, e_dst, cnt, scb, fill, epay);

  // 6-7: layer 1 (agg -> Z, pipelined GEMM -> bf16 h1 into Xb)
  dim3 ag1((NN + 15) / 16, NREL);
  aggz_kernel<<<ag1, 256, 0, stream>>>(Xb, scb, epay, Z, NN, MS1);
  gemmp_kernel<<<MS1 / GBM, 512, 0, stream>>>(Z, Wtb, bsum, Xb, NN, MS1);

  // 8: layer 2 fused (query slots only, f32 straight to d_out)
  fused2_kernel<<<MQ / GBM, 512, 0, stream>>>(Xb, scb, epay, qsrc, qdst,
                                              Wtb + (size_t)NREL * F * F, bsum + F,
                                              out, MQ);
}